// Round 1
// baseline (34.106 us; speedup 1.0000x reference)
//
#include <hip/hip_runtime.h>

#define NC 8  // NUM_CLASSES

// Count per-(batch, class): pred count, label count, intersection count.
// ws layout: ws[b*24 + 0..7] = P counts, [8..15] = L counts, [16..23] = I counts.
__global__ void __launch_bounds__(256) dice_count_kernel(
    const int* __restrict__ pred, const int* __restrict__ label,
    unsigned int* __restrict__ ws, int nvec_per_batch)
{
    const int b = blockIdx.y;
    const int4* p4 = reinterpret_cast<const int4*>(pred) + (size_t)b * nvec_per_batch;
    const int4* l4 = reinterpret_cast<const int4*>(label) + (size_t)b * nvec_per_batch;

    // 8 classes x 8-bit fields packed in a 64-bit accumulator.
    // Per-thread element count is <= 32 (grid sized below), so fields can't overflow.
    unsigned long long packP = 0, packL = 0, packI = 0;

    const int stride = gridDim.x * blockDim.x;
    for (int i = blockIdx.x * blockDim.x + threadIdx.x; i < nvec_per_batch; i += stride) {
        int4 pv = p4[i];
        int4 lv = l4[i];
        int pe[4] = {pv.x, pv.y, pv.z, pv.w};
        int le[4] = {lv.x, lv.y, lv.z, lv.w};
        #pragma unroll
        for (int j = 0; j < 4; ++j) {
            unsigned long long sp = 1ULL << (pe[j] * 8);
            unsigned long long sl = 1ULL << (le[j] * 8);
            packP += sp;
            packL += sl;
            packI += (pe[j] == le[j]) ? sp : 0ULL;
        }
    }

    // Unpack to 24 per-class counts (fully static indexing after unroll).
    unsigned cnt[3 * NC];
    #pragma unroll
    for (int c = 0; c < NC; ++c) {
        cnt[c]          = (unsigned)((packP >> (8 * c)) & 0xFFULL);
        cnt[NC + c]     = (unsigned)((packL >> (8 * c)) & 0xFFULL);
        cnt[2 * NC + c] = (unsigned)((packI >> (8 * c)) & 0xFFULL);
    }

    // Wave64 tree reduction.
    #pragma unroll
    for (int k = 0; k < 3 * NC; ++k) {
        #pragma unroll
        for (int off = 32; off > 0; off >>= 1)
            cnt[k] += __shfl_down(cnt[k], off, 64);
    }

    // Cross-wave reduction in LDS, then one global atomicAdd per counter per block.
    __shared__ unsigned s[3 * NC];
    if (threadIdx.x < 3 * NC) s[threadIdx.x] = 0;
    __syncthreads();
    if ((threadIdx.x & 63) == 0) {
        #pragma unroll
        for (int k = 0; k < 3 * NC; ++k)
            atomicAdd(&s[k], cnt[k]);
    }
    __syncthreads();
    if (threadIdx.x < 3 * NC)
        atomicAdd(&ws[b * 3 * NC + threadIdx.x], s[threadIdx.x]);
}

// score[c] = mean_b 2*I / (P + L + 1e-10)
__global__ void dice_final_kernel(const unsigned int* __restrict__ ws,
                                  float* __restrict__ out, int B)
{
    int c = threadIdx.x;
    if (c < NC) {
        float acc = 0.0f;
        for (int b = 0; b < B; ++b) {
            float P = (float)ws[b * 3 * NC + c];
            float L = (float)ws[b * 3 * NC + NC + c];
            float I = (float)ws[b * 3 * NC + 2 * NC + c];
            acc += 2.0f * I / (P + L + 1e-10f);
        }
        out[c] = acc / (float)B;
    }
}

extern "C" void kernel_launch(void* const* d_in, const int* in_sizes, int n_in,
                              void* d_out, int out_size, void* d_ws, size_t ws_size,
                              hipStream_t stream)
{
    const int* pred  = (const int*)d_in[0];
    const int* label = (const int*)d_in[1];
    float* out = (float*)d_out;
    unsigned int* ws = (unsigned int*)d_ws;

    const int n = in_sizes[0];        // 4*1*128*128*128 = 8388608
    const int B = 4;
    const int per_batch = n / B;      // 2097152
    const int nvec = per_batch / 4;   // 524288 int4 vectors per batch

    // Zero the 96 counters (harness poisons ws; it is NOT re-poisoned between replays).
    hipMemsetAsync(ws, 0, (size_t)(B * 3 * NC) * sizeof(unsigned int), stream);

    // 256 blocks/batch x 256 threads: each thread handles 8 int4 = 32 elements
    // per input -> packed 8-bit class fields can't overflow (32 < 255).
    dim3 grid(256, B);
    dice_count_kernel<<<grid, 256, 0, stream>>>(pred, label, ws, nvec);
    dice_final_kernel<<<1, 64, 0, stream>>>(ws, out, B);
}

// Round 2
// 31.009 us; speedup vs baseline: 1.0999x; 1.0999x over previous
//
#include <hip/hip_runtime.h>

#define NC 8        // NUM_CLASSES
#define NBLK 256    // blocks per batch in x
#define NB 4        // batch size
#define NROWS (NB * 3 * NC)  // 96 counter rows

// Per-(batch, class) counts: P = #{pred==c}, L = #{label==c}, I = #{pred==label==c}.
// Each block writes its 24 partial counts to ws[(b*24 + k)*NBLK + blockIdx.x]
// (transposed layout so the finalize kernel's reads coalesce). No atomics, no
// zero-init of ws needed: every slot is written unconditionally every call.
__global__ void __launch_bounds__(256) dice_count_kernel(
    const int* __restrict__ pred, const int* __restrict__ label,
    unsigned int* __restrict__ ws, int nvec_per_batch)
{
    const int b = blockIdx.y;
    const int4* p4 = reinterpret_cast<const int4*>(pred) + (size_t)b * nvec_per_batch;
    const int4* l4 = reinterpret_cast<const int4*>(label) + (size_t)b * nvec_per_batch;

    // 8 classes x 8-bit fields in a 64-bit accumulator. Per-thread element
    // count is 32 (grid sized below), so fields can't overflow (32 < 255).
    unsigned long long packP = 0, packL = 0, packI = 0;

    const int stride = gridDim.x * blockDim.x;
    for (int i = blockIdx.x * blockDim.x + threadIdx.x; i < nvec_per_batch; i += stride) {
        int4 pv = p4[i];
        int4 lv = l4[i];
        int pe[4] = {pv.x, pv.y, pv.z, pv.w};
        int le[4] = {lv.x, lv.y, lv.z, lv.w};
        #pragma unroll
        for (int j = 0; j < 4; ++j) {
            unsigned long long sp = 1ULL << (pe[j] * 8);
            unsigned long long sl = 1ULL << (le[j] * 8);
            packP += sp;
            packL += sl;
            packI += (pe[j] == le[j]) ? sp : 0ULL;
        }
    }

    // Unpack to 24 per-class counts (static indexing after unroll).
    unsigned cnt[3 * NC];
    #pragma unroll
    for (int c = 0; c < NC; ++c) {
        cnt[c]          = (unsigned)((packP >> (8 * c)) & 0xFFULL);
        cnt[NC + c]     = (unsigned)((packL >> (8 * c)) & 0xFFULL);
        cnt[2 * NC + c] = (unsigned)((packI >> (8 * c)) & 0xFFULL);
    }

    // Wave64 tree reduction.
    #pragma unroll
    for (int k = 0; k < 3 * NC; ++k) {
        #pragma unroll
        for (int off = 32; off > 0; off >>= 1)
            cnt[k] += __shfl_down(cnt[k], off, 64);
    }

    // Cross-wave reduction in LDS (4 waves), then direct per-block writes.
    __shared__ unsigned s[3 * NC];
    if (threadIdx.x < 3 * NC) s[threadIdx.x] = 0;
    __syncthreads();
    if ((threadIdx.x & 63) == 0) {
        #pragma unroll
        for (int k = 0; k < 3 * NC; ++k)
            atomicAdd(&s[k], cnt[k]);
    }
    __syncthreads();
    if (threadIdx.x < 3 * NC)
        ws[(b * 3 * NC + threadIdx.x) * NBLK + blockIdx.x] = s[threadIdx.x];
}

// One block, 512 threads = 8 waves. Each wave reduces 12 of the 96 rows
// (256 partials/row read as uint4, 1 load per lane), then 8 threads compute
// score[c] = mean_b 2*I / (P + L + 1e-10).
__global__ void __launch_bounds__(512) dice_final_kernel(
    const unsigned int* __restrict__ ws, float* __restrict__ out)
{
    __shared__ float tot[NROWS];
    const int wave = threadIdx.x >> 6;
    const int lane = threadIdx.x & 63;

    for (int r = wave; r < NROWS; r += 8) {
        const uint4* p = reinterpret_cast<const uint4*>(ws + (size_t)r * NBLK);
        uint4 v = p[lane];                       // 64 lanes x 4 = 256 partials
        unsigned sum = v.x + v.y + v.z + v.w;
        #pragma unroll
        for (int off = 32; off > 0; off >>= 1)
            sum += __shfl_down(sum, off, 64);
        if (lane == 0) tot[r] = (float)sum;
    }
    __syncthreads();

    if (threadIdx.x < NC) {
        const int c = threadIdx.x;
        float acc = 0.0f;
        #pragma unroll
        for (int b = 0; b < NB; ++b) {
            float P = tot[b * 3 * NC + c];
            float L = tot[b * 3 * NC + NC + c];
            float I = tot[b * 3 * NC + 2 * NC + c];
            acc += 2.0f * I / (P + L + 1e-10f);
        }
        out[c] = acc * (1.0f / NB);
    }
}

extern "C" void kernel_launch(void* const* d_in, const int* in_sizes, int n_in,
                              void* d_out, int out_size, void* d_ws, size_t ws_size,
                              hipStream_t stream)
{
    const int* pred  = (const int*)d_in[0];
    const int* label = (const int*)d_in[1];
    float* out = (float*)d_out;
    unsigned int* ws = (unsigned int*)d_ws;

    const int n = in_sizes[0];          // 4*1*128*128*128 = 8388608
    const int per_batch = n / NB;       // 2097152
    const int nvec = per_batch / 4;     // 524288 int4 vectors per batch

    // 256 blocks/batch x 256 threads: 8 int4 = 32 elements per thread.
    dim3 grid(NBLK, NB);
    dice_count_kernel<<<grid, 256, 0, stream>>>(pred, label, ws, nvec);
    dice_final_kernel<<<1, 512, 0, stream>>>(ws, out);
}